// Round 10
// baseline (103.151 us; speedup 1.0000x reference)
//
#include <hip/hip_runtime.h>
#include <math.h>

#define D 256
#define H 512
#define TT 10
#define THRESH 0.4f
#define KS 8          // K steps of 32 (D = 256)
#define NSPLIT 8      // scan blocks per graph
#define NQ 4          // H quarters
#define NTQ 8         // n-tiles (16 cols) per quarter

typedef __attribute__((ext_vector_type(8))) _Float16 half8;
typedef __attribute__((ext_vector_type(4))) float f32x4;

// ---------------------------------------------------------------------------
// K0: swizzle W1 [D][H] f32 -> fp16 MFMA B-fragments in ws (256 KB).
// layout (half8 = 16B units): idx = (n*8 + k)*64 + lane
//   element i = W1[k*32 + (lane>>4)*8 + i][n*16 + (lane&15)]
// quarter q (n = q*8..q*8+7) is a contiguous 64 KB slab.
// ---------------------------------------------------------------------------
__global__ __launch_bounds__(256) void w1_prep(const float* __restrict__ W1,
                                               short* __restrict__ W1s)
{
    const int tid = blockIdx.x * 256 + threadIdx.x;   // 16384 threads
    const int lane = tid & 63;
    const int cell = tid >> 6;                        // 0..255 = (n,k)
    const int k = cell & 7;
    const int n = cell >> 3;
    const int row0 = k * 32 + (lane >> 4) * 8;
    const int col = n * 16 + (lane & 15);
    _Float16 h8[8];
    #pragma unroll
    for (int i = 0; i < 8; ++i)
        h8[i] = (_Float16)W1[(size_t)(row0 + i) * H + col];   // RTN cvt
    *reinterpret_cast<half8*>(W1s + (((size_t)n * 8 + k) * 64 + lane) * 8) =
        *reinterpret_cast<half8*>(h8);
}

// ---------------------------------------------------------------------------
// K1: gate MLP first layer, fp16 1-term MFMA (fp16 err < bf16 2-term err).
// Grid: 256 row-blocks x 4 H-quarters. Block = 512 thr = 8 waves x 32 rows.
// The 64 KB W1-quarter is loaded into LDS ONCE (static), one barrier, then
// pure compute: no streaming, no vmcnt bookkeeping, no double buffer.
// VGPR ~105 (A frags 64) -> 4 waves/SIMD; waves stagger n-tile order.
// Emits per-quarter partial logits lpq[q][row].
// ---------------------------------------------------------------------------
__global__ __launch_bounds__(512, 4) void gate_mfma(
    const float* __restrict__ h_sub,
    const short* __restrict__ W1s,
    const float* __restrict__ b1,
    const float* __restrict__ W2,
    float* __restrict__ lpq,           // [NQ][S]
    int S)
{
    __shared__ __align__(16) short sB[NTQ * KS * 64 * 8];   // 64 KB
    __shared__ float sb1[128], sw2[128];
    const int tid = threadIdx.x;
    const int lane = tid & 63;
    const int w = tid >> 6;            // 0..7
    const int rb = blockIdx.x >> 2;
    const int q = blockIdx.x & 3;
    const int base = rb * 256 + w * 32;

    // stage this quarter's 64 KB of B-fragments: 512 thr x 8 float4
    {
        const float4* src = reinterpret_cast<const float4*>(W1s + (size_t)q * 32768);
        float4* dst = reinterpret_cast<float4*>(sB);
        #pragma unroll
        for (int i = 0; i < 8; ++i) dst[i * 512 + tid] = src[i * 512 + tid];
        if (tid < 128) { sb1[tid] = b1[q * 128 + tid]; sw2[tid] = W2[q * 128 + tid]; }
    }

    // A fragments fp16: 2 s-tiles x 8 k = 64 VGPR
    half8 af[2][KS];
    #pragma unroll
    for (int s = 0; s < 2; ++s) {
        const int row = base + s * 16 + (lane & 15);
        const float* rp = h_sub + (size_t)row * D + (lane >> 4) * 8;
        #pragma unroll
        for (int k = 0; k < KS; ++k) {
            float x[8];
            *reinterpret_cast<float4*>(&x[0]) =
                *reinterpret_cast<const float4*>(rp + k * 32);
            *reinterpret_cast<float4*>(&x[4]) =
                *reinterpret_cast<const float4*>(rp + k * 32 + 4);
            _Float16 h8[8];
            #pragma unroll
            for (int i = 0; i < 8; ++i) h8[i] = (_Float16)x[i];
            af[s][k] = *reinterpret_cast<half8*>(h8);
        }
    }

    __syncthreads();   // B-quarter + b1/w2 visible; then pure compute

    float lp[2][4] = {{0.f,0.f,0.f,0.f},{0.f,0.f,0.f,0.f}};

    #pragma unroll
    for (int nn = 0; nn < NTQ; ++nn) {
        const int n = (nn + w) & 7;          // stagger waves across n-tiles
        f32x4 acc[2];
        acc[0] = (f32x4){0.f,0.f,0.f,0.f};
        acc[1] = (f32x4){0.f,0.f,0.f,0.f};
        __builtin_amdgcn_s_setprio(1);
        #pragma unroll
        for (int k = 0; k < KS; ++k) {
            half8 bh = *reinterpret_cast<const half8*>(
                sB + ((n * 8 + k) * 64 + lane) * 8);
            acc[0] = __builtin_amdgcn_mfma_f32_16x16x32_f16(af[0][k], bh, acc[0], 0, 0, 0);
            acc[1] = __builtin_amdgcn_mfma_f32_16x16x32_f16(af[1][k], bh, acc[1], 0, 0, 0);
        }
        __builtin_amdgcn_s_setprio(0);
        // epilogue for these 16 hidden cols: +b1, relu, dot W2 (f32)
        const int hc = n * 16 + (lane & 15);
        const float b1h = sb1[hc], w2h = sw2[hc];
        #pragma unroll
        for (int s = 0; s < 2; ++s)
            #pragma unroll
            for (int j = 0; j < 4; ++j) {
                float v = acc[s][j] + b1h;
                v = v > 0.f ? v : 0.f;
                lp[s][j] = fmaf(v, w2h, lp[s][j]);
            }
    }

    // butterfly over the 16 h-cols (low 4 lane bits)
    #pragma unroll
    for (int m = 1; m < 16; m <<= 1)
        #pragma unroll
        for (int s = 0; s < 2; ++s)
            #pragma unroll
            for (int j = 0; j < 4; ++j)
                lp[s][j] += __shfl_xor(lp[s][j], m);

    if ((lane & 15) == 0) {
        const int g = lane >> 4;
        #pragma unroll
        for (int s = 0; s < 2; ++s)
            #pragma unroll
            for (int j = 0; j < 4; ++j)
                lpq[(size_t)q * S + base + s * 16 + g * 4 + j] = lp[s][j];
    }
}

// ---------------------------------------------------------------------------
// K1b: combine quarter partials -> sigmoid, submask, gate bit-array
// ---------------------------------------------------------------------------
__global__ __launch_bounds__(256) void gate_fin(
    const float* __restrict__ lpq,     // [NQ][S]
    const float* __restrict__ b2,
    float* __restrict__ submask,       // [S]
    unsigned* __restrict__ gbits,      // [S/32]
    int S)
{
    const int row = blockIdx.x * 256 + threadIdx.x;
    const float logit = lpq[row] + lpq[S + row] + lpq[2 * S + row]
                      + lpq[3 * S + row] + b2[0];
    const float sig = 1.f / (1.f + expf(-logit));
    submask[row] = sig;
    unsigned long long bal = __ballot(sig > THRESH);
    if ((threadIdx.x & 63) == 0) {
        const int w0 = row >> 5;
        gbits[w0] = (unsigned)bal;
        gbits[w0 + 1] = (unsigned)(bal >> 32);
    }
}

// ---------------------------------------------------------------------------
// K2a: mask scan, NSPLIT blocks per graph -> partial sums/counts in ws
// ---------------------------------------------------------------------------
__global__ __launch_bounds__(256) void seg_scan(
    const float* __restrict__ h_sub,    // [S][D]
    const int*   __restrict__ mask,     // [B][S]
    const unsigned* __restrict__ gbits, // [S/32]
    float* __restrict__ psum,           // [B*NSPLIT][D]
    int*   __restrict__ pcnt,           // [B*NSPLIT]
    int S)
{
    const int i = blockIdx.x / NSPLIT;
    const int p = blockIdx.x % NSPLIT;
    const int tid = threadIdx.x;
    const int lane = tid & 63;
    const int w = tid >> 6;
    const int seg = S / NSPLIT;                 // 8192
    const int start = p * seg;
    const int* mrow = mask + (size_t)i * S + start;

    __shared__ unsigned sbits[8192 / 32];       // 256 words = 1 KB
    {
        const int nw = seg / 32;
        for (int t = tid; t < nw; t += 256) sbits[t] = gbits[(start >> 5) + t];
    }
    __syncthreads();

    float4 acc = make_float4(0.f, 0.f, 0.f, 0.f);
    int cnt = 0;

    const int per = seg / 4;                    // per wave: 2048
    for (int base = w * per; base < (w + 1) * per; base += 256) {
        const int j0 = base + (lane << 2);
        int4 m4 = *reinterpret_cast<const int4*>(mrow + j0);
        const unsigned bw = sbits[j0 >> 5];
        const int sh = j0 & 31;
        unsigned long long bal[4];
        bal[0] = __ballot((m4.x != 0) & ((bw >> (sh + 0)) & 1u));
        bal[1] = __ballot((m4.y != 0) & ((bw >> (sh + 1)) & 1u));
        bal[2] = __ballot((m4.z != 0) & ((bw >> (sh + 2)) & 1u));
        bal[3] = __ballot((m4.w != 0) & ((bw >> (sh + 3)) & 1u));
        #pragma unroll
        for (int s = 0; s < 4; ++s) {
            unsigned long long b = bal[s];
            while (b) {
                int t = __builtin_ctzll(b);
                b &= b - 1;
                int jj = start + base + (t << 2) + s;
                float4 hv = *reinterpret_cast<const float4*>(
                    h_sub + (size_t)jj * D + (lane << 2));
                acc.x += hv.x; acc.y += hv.y; acc.z += hv.z; acc.w += hv.w;
                cnt++;
            }
        }
    }

    __shared__ float ssum[4][D];
    __shared__ int   scnt[4];
    *reinterpret_cast<float4*>(&ssum[w][lane << 2]) = acc;
    if (lane == 0) scnt[w] = cnt;
    __syncthreads();

    float a = ssum[0][tid] + ssum[1][tid] + ssum[2][tid] + ssum[3][tid];
    psum[(size_t)blockIdx.x * D + tid] = a;
    if (tid == 0) pcnt[blockIdx.x] = scnt[0] + scnt[1] + scnt[2] + scnt[3];
}

// ---------------------------------------------------------------------------
// K2b: combine partials -> mean, cosine, classifier logits
// ---------------------------------------------------------------------------
__global__ __launch_bounds__(256) void seg_combine(
    const float* __restrict__ h_graph,  // [B][D]
    const float* __restrict__ psum,     // [B*NSPLIT][D]
    const int*   __restrict__ pcnt,     // [B*NSPLIT]
    const float* __restrict__ Wc,       // [2D][TT]
    const float* __restrict__ bc,       // [TT]
    float* __restrict__ logits,         // [B][TT]
    float* __restrict__ cos_ws)         // [B]
{
    const int i = blockIdx.x;
    const int tid = threadIdx.x;
    const int lane = tid & 63;
    const int w = tid >> 6;

    float a = 0.f;
    int c = 0;
    #pragma unroll
    for (int p = 0; p < NSPLIT; ++p) {
        a += psum[((size_t)i * NSPLIT + p) * D + tid];
        c += pcnt[i * NSPLIT + p];
    }
    a = (c > 0) ? (a / (float)c) : 0.f;
    const float g = h_graph[(size_t)i * D + tid];

    float r0 = a * a, r1 = g * g, r2 = a * g;
    #pragma unroll
    for (int m = 1; m < 64; m <<= 1) {
        r0 += __shfl_xor(r0, m);
        r1 += __shfl_xor(r1, m);
        r2 += __shfl_xor(r2, m);
    }
    __shared__ float red[4][3];
    if (lane == 0) { red[w][0] = r0; red[w][1] = r1; red[w][2] = r2; }
    __syncthreads();
    if (tid == 0) {
        float a2 = red[0][0] + red[1][0] + red[2][0] + red[3][0];
        float g2 = red[0][1] + red[1][1] + red[2][1] + red[3][1];
        float ag = red[0][2] + red[1][2] + red[2][2] + red[3][2];
        float an = sqrtf(a2), gn = sqrtf(g2);
        float cs = (c > 0) ? (ag / (fmaxf(an, 1e-12f) * fmaxf(gn, 1e-12f))) : 0.f;
        cos_ws[i] = cs;
    }

    float lg[TT];
    #pragma unroll
    for (int t = 0; t < TT; ++t)
        lg[t] = g * Wc[(size_t)tid * TT + t] + a * Wc[(size_t)(D + tid) * TT + t];
    #pragma unroll
    for (int m = 1; m < 64; m <<= 1)
        #pragma unroll
        for (int t = 0; t < TT; ++t) lg[t] += __shfl_xor(lg[t], m);
    __shared__ float lpart[4][TT];
    if (lane == 0)
        #pragma unroll
        for (int t = 0; t < TT; ++t) lpart[w][t] = lg[t];
    __syncthreads();
    if (tid < TT)
        logits[(size_t)i * TT + tid] =
            lpart[0][tid] + lpart[1][tid] + lpart[2][tid] + lpart[3][tid] + bc[tid];
}

// ---------------------------------------------------------------------------
__global__ void loss_kernel(const float* __restrict__ cos_ws,
                            float* __restrict__ out, int B)
{
    const int lane = threadIdx.x;
    float s = 0.f;
    for (int i = lane; i < B; i += 64) s += cos_ws[i];
    #pragma unroll
    for (int m = 1; m < 64; m <<= 1) s += __shfl_xor(s, m);
    if (lane == 0) out[0] = 1.0f - s / (float)B;
}

// ---------------------------------------------------------------------------
extern "C" void kernel_launch(void* const* d_in, const int* in_sizes, int n_in,
                              void* d_out, int out_size, void* d_ws, size_t ws_size,
                              hipStream_t stream)
{
    const float* h_graph = (const float*)d_in[0];
    const float* h_sub   = (const float*)d_in[1];
    const float* W1      = (const float*)d_in[2];
    const float* b1      = (const float*)d_in[3];
    const float* W2      = (const float*)d_in[4];
    const float* b2      = (const float*)d_in[5];
    const float* Wc      = (const float*)d_in[6];
    const float* bc      = (const float*)d_in[7];
    const int*   mask    = (const int*)d_in[8];

    const int B = in_sizes[0] / D;
    const int S = in_sizes[1] / D;

    float* out     = (float*)d_out;
    float* logits  = out;                       // [B*TT]
    float* loss    = out + (size_t)B * TT;      // [1]
    float* submask = loss + 1;                  // [S]

    char* ws = (char*)d_ws;
    short*    W1s    = (short*)ws;                       // 256 KB fp16 frags
    unsigned* gbits  = (unsigned*)(ws + 512 * 1024);     // 8 KB
    int*      pcnt   = (int*)(ws + 528 * 1024);          // 16 KB
    float*    cos_ws = (float*)(ws + 560 * 1024);        // 2 KB
    float*    lpq    = (float*)(ws + 1024 * 1024);       // 1 MB [NQ][S]
    float*    psum   = (float*)(ws + 2 * 1024 * 1024);   // 4 MB

    w1_prep<<<64, 256, 0, stream>>>(W1, W1s);
    gate_mfma<<<(S / 256) * NQ, 512, 0, stream>>>(h_sub, W1s, b1, W2, lpq, S);
    gate_fin<<<S / 256, 256, 0, stream>>>(lpq, b2, submask, gbits, S);
    seg_scan<<<B * NSPLIT, 256, 0, stream>>>(h_sub, mask, gbits, psum, pcnt, S);
    seg_combine<<<B, 256, 0, stream>>>(h_graph, psum, pcnt, Wc, bc, logits, cos_ws);
    loss_kernel<<<1, 64, 0, stream>>>(cos_ws, loss, B);
}

// Round 11
// 77.330 us; speedup vs baseline: 1.3339x; 1.3339x over previous
//
#include <hip/hip_runtime.h>
#include <math.h>

#define D 256
#define H 512
#define TT 10
#define THRESH 0.4f
#define KS 8          // K steps of 32 (D = 256)
#define NSPLIT 8      // scan blocks per graph

typedef __attribute__((ext_vector_type(8))) _Float16 half8;
typedef __attribute__((ext_vector_type(4))) float f32x4;

// ---------------------------------------------------------------------------
// K0: swizzle W1 [D][H] f32 -> fp16 MFMA B-fragments in ws (256 KB).
// layout (half8 = 16B units): idx = (n*8 + k)*64 + lane
//   element i = W1[k*32 + (lane>>4)*8 + i][n*16 + (lane&15)]
// each n-tile (16 cols) is a contiguous 8 KB chunk.
// ---------------------------------------------------------------------------
__global__ __launch_bounds__(256) void w1_prep(const float* __restrict__ W1,
                                               short* __restrict__ W1s)
{
    const int tid = blockIdx.x * 256 + threadIdx.x;   // 16384 threads
    const int lane = tid & 63;
    const int cell = tid >> 6;                        // 0..255 = (n,k)
    const int k = cell & 7;
    const int n = cell >> 3;
    const int row0 = k * 32 + (lane >> 4) * 8;
    const int col = n * 16 + (lane & 15);
    _Float16 h8[8];
    #pragma unroll
    for (int i = 0; i < 8; ++i)
        h8[i] = (_Float16)W1[(size_t)(row0 + i) * H + col];   // RTN
    *reinterpret_cast<half8*>(W1s + (((size_t)n * 8 + k) * 64 + lane) * 8) =
        *reinterpret_cast<half8*>(h8);
}

// ---------------------------------------------------------------------------
// K1: gate MLP, fp16 1-term MFMA (fp16 err ~5e-4 < bf16 2-term).
// 256-thread blocks = 4 INDEPENDENT waves, 32 rows each, full H per wave.
// Per-wave private 2 x 8 KB LDS double buffer, global_load_lds(16B),
// counted vmcnt(8), zero steady-state barriers.
// PER-WAVE CHUNK ROTATION: wave g starts at chunk (g&31) — SIMD-mates are
// phase-shifted (stalls mutually covered) and W1s reads spread over 256 KB.
// LDS 68 KB -> 2 blocks/CU = 2 waves/SIMD.
// ---------------------------------------------------------------------------
__global__ __launch_bounds__(256, 2) void gate_mfma(
    const float* __restrict__ h_sub,
    const short* __restrict__ W1s,
    const float* __restrict__ b1,
    const float* __restrict__ W2,
    const float* __restrict__ b2,
    float* __restrict__ submask,
    unsigned* __restrict__ gbits)      // [S/32]
{
    __shared__ __align__(16) short sW[4][2][4096];   // per-wave 2 x 8 KB
    __shared__ float sb1[H], sw2[H];
    const int tid = threadIdx.x;
    const int lane = tid & 63;
    const int w = tid >> 6;            // wave id 0..3
    const int base = blockIdx.x * 128 + w * 32;
    const int rot = (blockIdx.x * 4 + w) & 31;       // chunk rotation
    const float bb = b2[0];

    // stage b1 / W2 into LDS (visible after the one barrier)
    {
        int i = tid * 2;
        *reinterpret_cast<float2*>(&sb1[i]) = *reinterpret_cast<const float2*>(&b1[i]);
        *reinterpret_cast<float2*>(&sw2[i]) = *reinterpret_cast<const float2*>(&W2[i]);
    }

    // A fragments fp16: 2 s-tiles x 8 k = 64 VGPR
    half8 af[2][KS];
    #pragma unroll
    for (int s = 0; s < 2; ++s) {
        const int row = base + s * 16 + (lane & 15);
        const float* rp = h_sub + (size_t)row * D + (lane >> 4) * 8;
        #pragma unroll
        for (int k = 0; k < KS; ++k) {
            float x[8];
            *reinterpret_cast<float4*>(&x[0]) =
                *reinterpret_cast<const float4*>(rp + k * 32);
            *reinterpret_cast<float4*>(&x[4]) =
                *reinterpret_cast<const float4*>(rp + k * 32 + 4);
            _Float16 h8[8];
            #pragma unroll
            for (int i = 0; i < 8; ++i) h8[i] = (_Float16)x[i];
            af[s][k] = *reinterpret_cast<half8*>(h8);
        }
    }

    // one barrier: sb1/sw2 visible to all waves AND all prologue vmem
    // drained (hipcc emits s_waitcnt vmcnt(0) before s_barrier), so the
    // counted-vmcnt bookkeeping below starts from zero.
    __syncthreads();

    // stage n-tile chunk c (8 KB) into THIS wave's buffer b: 8 loads
    auto stage = [&](int c, int b) {
        const char* gp = (const char*)W1s + ((size_t)(c & 31) << 13)
                       + (size_t)lane * 16;
        char* lp0 = (char*)&sW[w][b][0] + lane * 16;
        #pragma unroll
        for (int i = 0; i < 8; ++i) {
            __builtin_amdgcn_global_load_lds(
                (const __attribute__((address_space(1))) void*)(gp + i * 1024),
                (__attribute__((address_space(3))) void*)(lp0 + i * 1024),
                16, 0, 0);
        }
    };

    stage(rot, 0);
    stage(rot + 1, 1);

    float lp[2][4] = {{0.f,0.f,0.f,0.f},{0.f,0.f,0.f,0.f}};

    for (int cc = 0; cc < 32; ++cc) {
        // chunk cc landed; chunk cc+1's 8 loads stay in flight
        if (cc < 31) asm volatile("s_waitcnt vmcnt(8)" ::: "memory");
        else         asm volatile("s_waitcnt vmcnt(0)" ::: "memory");
        __builtin_amdgcn_sched_barrier(0);

        const int c = (cc + rot) & 31;       // actual n-tile index
        const short* buf = &sW[w][cc & 1][0];
        f32x4 acc[2];
        acc[0] = (f32x4){0.f,0.f,0.f,0.f};
        acc[1] = (f32x4){0.f,0.f,0.f,0.f};

        #pragma unroll
        for (int k = 0; k < KS; ++k) {
            half8 bh = *reinterpret_cast<const half8*>(buf + (k * 64 + lane) * 8);
            acc[0] = __builtin_amdgcn_mfma_f32_16x16x32_f16(af[0][k], bh, acc[0], 0, 0, 0);
            acc[1] = __builtin_amdgcn_mfma_f32_16x16x32_f16(af[1][k], bh, acc[1], 0, 0, 0);
        }

        // epilogue for these 16 hidden cols: +b1, relu, dot W2 (f32)
        const int h = c * 16 + (lane & 15);
        const float b1h = sb1[h], w2h = sw2[h];
        #pragma unroll
        for (int s = 0; s < 2; ++s)
            #pragma unroll
            for (int j = 0; j < 4; ++j) {
                float v = acc[s][j] + b1h;
                v = v > 0.f ? v : 0.f;
                lp[s][j] = fmaf(v, w2h, lp[s][j]);
            }

        __builtin_amdgcn_sched_barrier(0);
        if (cc < 30) stage(cc + rot + 2, cc & 1);   // refill finished buf
    }

    // butterfly over the 16 h-cols (low 4 lane bits)
    #pragma unroll
    for (int m = 1; m < 16; m <<= 1)
        #pragma unroll
        for (int s = 0; s < 2; ++s)
            #pragma unroll
            for (int j = 0; j < 4; ++j)
                lp[s][j] += __shfl_xor(lp[s][j], m);

    // rows: s*16 + g*4 + j  (g = lane>>4)
    const int g = lane >> 4;
    unsigned bits = 0;
    float sig[2][4];
    #pragma unroll
    for (int s = 0; s < 2; ++s)
        #pragma unroll
        for (int j = 0; j < 4; ++j) {
            sig[s][j] = 1.f / (1.f + expf(-(lp[s][j] + bb)));
            if (sig[s][j] > THRESH) bits |= 1u << (s * 16 + g * 4 + j);
        }
    bits |= __shfl_xor(bits, 16);
    bits |= __shfl_xor(bits, 32);
    if (lane == 0) gbits[blockIdx.x * 4 + w] = bits;

    if ((lane & 15) == 0)
        #pragma unroll
        for (int s = 0; s < 2; ++s)
            #pragma unroll
            for (int j = 0; j < 4; ++j)
                submask[base + s * 16 + g * 4 + j] = sig[s][j];
}

// ---------------------------------------------------------------------------
// K2a: mask scan, NSPLIT blocks per graph -> partial sums/counts in ws
// ---------------------------------------------------------------------------
__global__ __launch_bounds__(256) void seg_scan(
    const float* __restrict__ h_sub,    // [S][D]
    const int*   __restrict__ mask,     // [B][S]
    const unsigned* __restrict__ gbits, // [S/32]
    float* __restrict__ psum,           // [B*NSPLIT][D]
    int*   __restrict__ pcnt,           // [B*NSPLIT]
    int S)
{
    const int i = blockIdx.x / NSPLIT;
    const int p = blockIdx.x % NSPLIT;
    const int tid = threadIdx.x;
    const int lane = tid & 63;
    const int w = tid >> 6;
    const int seg = S / NSPLIT;                 // 8192
    const int start = p * seg;
    const int* mrow = mask + (size_t)i * S + start;

    __shared__ unsigned sbits[8192 / 32];       // 256 words = 1 KB
    {
        const int nw = seg / 32;
        for (int t = tid; t < nw; t += 256) sbits[t] = gbits[(start >> 5) + t];
    }
    __syncthreads();

    float4 acc = make_float4(0.f, 0.f, 0.f, 0.f);
    int cnt = 0;

    const int per = seg / 4;                    // per wave: 2048
    for (int base = w * per; base < (w + 1) * per; base += 256) {
        const int j0 = base + (lane << 2);
        int4 m4 = *reinterpret_cast<const int4*>(mrow + j0);
        const unsigned bw = sbits[j0 >> 5];
        const int sh = j0 & 31;
        unsigned long long bal[4];
        bal[0] = __ballot((m4.x != 0) & ((bw >> (sh + 0)) & 1u));
        bal[1] = __ballot((m4.y != 0) & ((bw >> (sh + 1)) & 1u));
        bal[2] = __ballot((m4.z != 0) & ((bw >> (sh + 2)) & 1u));
        bal[3] = __ballot((m4.w != 0) & ((bw >> (sh + 3)) & 1u));
        #pragma unroll
        for (int s = 0; s < 4; ++s) {
            unsigned long long b = bal[s];
            while (b) {
                int t = __builtin_ctzll(b);
                b &= b - 1;
                int jj = start + base + (t << 2) + s;
                float4 hv = *reinterpret_cast<const float4*>(
                    h_sub + (size_t)jj * D + (lane << 2));
                acc.x += hv.x; acc.y += hv.y; acc.z += hv.z; acc.w += hv.w;
                cnt++;
            }
        }
    }

    __shared__ float ssum[4][D];
    __shared__ int   scnt[4];
    *reinterpret_cast<float4*>(&ssum[w][lane << 2]) = acc;
    if (lane == 0) scnt[w] = cnt;
    __syncthreads();

    float a = ssum[0][tid] + ssum[1][tid] + ssum[2][tid] + ssum[3][tid];
    psum[(size_t)blockIdx.x * D + tid] = a;
    if (tid == 0) pcnt[blockIdx.x] = scnt[0] + scnt[1] + scnt[2] + scnt[3];
}

// ---------------------------------------------------------------------------
// K2b: combine partials -> mean, cosine, classifier logits
// ---------------------------------------------------------------------------
__global__ __launch_bounds__(256) void seg_combine(
    const float* __restrict__ h_graph,  // [B][D]
    const float* __restrict__ psum,     // [B*NSPLIT][D]
    const int*   __restrict__ pcnt,     // [B*NSPLIT]
    const float* __restrict__ Wc,       // [2D][TT]
    const float* __restrict__ bc,       // [TT]
    float* __restrict__ logits,         // [B][TT]
    float* __restrict__ cos_ws)         // [B]
{
    const int i = blockIdx.x;
    const int tid = threadIdx.x;
    const int lane = tid & 63;
    const int w = tid >> 6;

    float a = 0.f;
    int c = 0;
    #pragma unroll
    for (int p = 0; p < NSPLIT; ++p) {
        a += psum[((size_t)i * NSPLIT + p) * D + tid];
        c += pcnt[i * NSPLIT + p];
    }
    a = (c > 0) ? (a / (float)c) : 0.f;
    const float g = h_graph[(size_t)i * D + tid];

    float r0 = a * a, r1 = g * g, r2 = a * g;
    #pragma unroll
    for (int m = 1; m < 64; m <<= 1) {
        r0 += __shfl_xor(r0, m);
        r1 += __shfl_xor(r1, m);
        r2 += __shfl_xor(r2, m);
    }
    __shared__ float red[4][3];
    if (lane == 0) { red[w][0] = r0; red[w][1] = r1; red[w][2] = r2; }
    __syncthreads();
    if (tid == 0) {
        float a2 = red[0][0] + red[1][0] + red[2][0] + red[3][0];
        float g2 = red[0][1] + red[1][1] + red[2][1] + red[3][1];
        float ag = red[0][2] + red[1][2] + red[2][2] + red[3][2];
        float an = sqrtf(a2), gn = sqrtf(g2);
        float cs = (c > 0) ? (ag / (fmaxf(an, 1e-12f) * fmaxf(gn, 1e-12f))) : 0.f;
        cos_ws[i] = cs;
    }

    float lg[TT];
    #pragma unroll
    for (int t = 0; t < TT; ++t)
        lg[t] = g * Wc[(size_t)tid * TT + t] + a * Wc[(size_t)(D + tid) * TT + t];
    #pragma unroll
    for (int m = 1; m < 64; m <<= 1)
        #pragma unroll
        for (int t = 0; t < TT; ++t) lg[t] += __shfl_xor(lg[t], m);
    __shared__ float lpart[4][TT];
    if (lane == 0)
        #pragma unroll
        for (int t = 0; t < TT; ++t) lpart[w][t] = lg[t];
    __syncthreads();
    if (tid < TT)
        logits[(size_t)i * TT + tid] =
            lpart[0][tid] + lpart[1][tid] + lpart[2][tid] + lpart[3][tid] + bc[tid];
}

// ---------------------------------------------------------------------------
__global__ void loss_kernel(const float* __restrict__ cos_ws,
                            float* __restrict__ out, int B)
{
    const int lane = threadIdx.x;
    float s = 0.f;
    for (int i = lane; i < B; i += 64) s += cos_ws[i];
    #pragma unroll
    for (int m = 1; m < 64; m <<= 1) s += __shfl_xor(s, m);
    if (lane == 0) out[0] = 1.0f - s / (float)B;
}

// ---------------------------------------------------------------------------
extern "C" void kernel_launch(void* const* d_in, const int* in_sizes, int n_in,
                              void* d_out, int out_size, void* d_ws, size_t ws_size,
                              hipStream_t stream)
{
    const float* h_graph = (const float*)d_in[0];
    const float* h_sub   = (const float*)d_in[1];
    const float* W1      = (const float*)d_in[2];
    const float* b1      = (const float*)d_in[3];
    const float* W2      = (const float*)d_in[4];
    const float* b2      = (const float*)d_in[5];
    const float* Wc      = (const float*)d_in[6];
    const float* bc      = (const float*)d_in[7];
    const int*   mask    = (const int*)d_in[8];

    const int B = in_sizes[0] / D;
    const int S = in_sizes[1] / D;

    float* out     = (float*)d_out;
    float* logits  = out;                       // [B*TT]
    float* loss    = out + (size_t)B * TT;      // [1]
    float* submask = loss + 1;                  // [S]

    char* ws = (char*)d_ws;
    short*    W1s    = (short*)ws;                       // 256 KB fp16 frags
    unsigned* gbits  = (unsigned*)(ws + 512 * 1024);     // 8 KB
    int*      pcnt   = (int*)(ws + 528 * 1024);          // 16 KB
    float*    cos_ws = (float*)(ws + 560 * 1024);        // 2 KB
    float*    psum   = (float*)(ws + 1024 * 1024);       // 4 MB

    w1_prep<<<64, 256, 0, stream>>>(W1, W1s);
    gate_mfma<<<S / 128, 256, 0, stream>>>(h_sub, W1s, b1, W2, b2, submask, gbits);
    seg_scan<<<B * NSPLIT, 256, 0, stream>>>(h_sub, mask, gbits, psum, pcnt, S);
    seg_combine<<<B, 256, 0, stream>>>(h_graph, psum, pcnt, Wc, bc, logits, cos_ws);
    loss_kernel<<<1, 64, 0, stream>>>(cos_ws, loss, B);
}